// Round 7
// baseline (570.703 us; speedup 1.0000x reference)
//
#include <hip/hip_runtime.h>
#include <hip/hip_bf16.h>

#define NN 50000
#define NE 800000
#define F 128     // input feature dim (= K)
#define HD 128    // output dim = H*DH (= N)
#define H 4

typedef __attribute__((ext_vector_type(4))) float f32x4;
typedef __attribute__((ext_vector_type(8))) __bf16 bf16x8;

// ---------- helpers ----------

// mish(x) = x * tanh(softplus(x)) = x * (u-1)/(u+1), u = (1+e^x)^2
__device__ __forceinline__ float mish_f(float x) {
    if (x > 30.f) return x;
    float t = __expf(x);
    float u = 1.f + t;
    u = u * u;
    return x * (u - 1.f) * __builtin_amdgcn_rcpf(u + 1.f);
}

__device__ __forceinline__ unsigned f32_to_bf16(float x) {
    unsigned u = __float_as_uint(x);
    u += 0x7FFFu + ((u >> 16) & 1u);
    return u >> 16;
}
__device__ __forceinline__ float bf16lo_to_f32(unsigned p) {
    return __uint_as_float((p & 0xFFFFu) << 16);
}
__device__ __forceinline__ float bf16hi_to_f32(unsigned p) {
    return __uint_as_float(p & 0xFFFF0000u);
}

// ---------- prep: W f32[128k x 128n] -> bf16 fragment-ordered ----------
__global__ __launch_bounds__(256) void prep_w(
    const float* __restrict__ W0, const float* __restrict__ W1,
    const float* __restrict__ W2, uint4* __restrict__ O)
{
    int b = blockIdx.x;
    const float* W = (b == 0) ? W0 : (b == 1) ? W1 : W2;
    uint4* out = O + b * 2048;
    for (int c = threadIdx.x; c < 2048; c += 256) {
        int fn = c >> 8, ks = (c >> 6) & 3, lane = c & 63;
        int lgp = lane >> 4, l15 = lane & 15;
        int col = fn * 16 + l15, k0 = ks * 32 + lgp * 8;
        unsigned u[4];
        #pragma unroll
        for (int i = 0; i < 4; ++i) {
            float a = W[(k0 + 2 * i) * 128 + col];
            float bb = W[(k0 + 2 * i + 1) * 128 + col];
            u[i] = f32_to_bf16(a) | (f32_to_bf16(bb) << 16);
        }
        out[c] = make_uint4(u[0], u[1], u[2], u[3]);
    }
}

// ---------- CSR build ----------
__global__ __launch_bounds__(256) void hist_kernel(
    const int* __restrict__ receivers, unsigned* __restrict__ cnt)
{
    int i = blockIdx.x * 256 + threadIdx.x;
    if (i < NE) atomicAdd(&cnt[receivers[i]], 1u);
}

__global__ __launch_bounds__(1024) void scan_kernel(
    const unsigned* __restrict__ cnt, unsigned* __restrict__ rowptr)
{
    __shared__ unsigned part[1024];
    const int t = threadIdx.x;
    const int C = (NN + 1023) / 1024;
    int base = t * C;
    unsigned s = 0;
    for (int i = 0; i < C; ++i) {
        int idx = base + i;
        if (idx < NN) s += cnt[idx];
    }
    part[t] = s;
    __syncthreads();
    for (int off = 1; off < 1024; off <<= 1) {
        unsigned v = (t >= off) ? part[t - off] : 0u;
        __syncthreads();
        if (t >= off) part[t] += v;
        __syncthreads();
    }
    unsigned run = part[t] - s;
    for (int i = 0; i < C; ++i) {
        int idx = base + i;
        if (idx < NN) { rowptr[idx] = run; run += cnt[idx]; }
    }
    if (t == 1023) rowptr[NN] = run;
}

// scatter + inverse map jof: edge e lands at perm position jof[e]
__global__ __launch_bounds__(256) void scatter_kernel(
    const int* __restrict__ receivers, const unsigned* __restrict__ rowptr,
    unsigned* __restrict__ cnt2, unsigned* __restrict__ jof)
{
    int i = blockIdx.x * 256 + threadIdx.x;
    if (i >= NE) return;
    int r = receivers[i];
    unsigned pos = rowptr[r] + atomicAdd(&cnt2[r], 1u);
    jof[i] = pos;
}

// ---------- both node projections in one kernel ----------
// Sp/Rp layout (bf16 packed): node row = 32 uint2 (256 B); uint2 at
// idx=wc*16+l15 holds cols {wc*64 + n*16 + l15 : n=0..3} as 4 bf16
__global__ __launch_bounds__(256, 4) void proj_both(
    const float* __restrict__ X,
    const bf16x8* __restrict__ Wf0, const bf16x8* __restrict__ Wf1,
    const float* __restrict__ b0, const float* __restrict__ b1,
    int M, uint2* __restrict__ Sp, uint2* __restrict__ Rp)
{
    __shared__ __align__(16) char ldsA[32768];
    const int t = threadIdx.x;
    const int lane = t & 63;
    const int wid = t >> 6;
    const int wr = wid >> 1, wc = wid & 1;
    const int l15 = lane & 15, lgp = lane >> 4;
    const size_t rowbase = (size_t)blockIdx.x * 128;

    #pragma unroll
    for (int i = 0; i < 8; ++i) {
        int c = i * 256 + t;
        int row = c >> 4, cc = c & 15;
        size_t e = rowbase + row;
        uint4 p = make_uint4(0, 0, 0, 0);
        if (e < (size_t)M) {
            const float4* src = (const float4*)(X + e * F + cc * 8);
            float4 f0 = src[0], f1 = src[1];
            p.x = f32_to_bf16(f0.x) | (f32_to_bf16(f0.y) << 16);
            p.y = f32_to_bf16(f0.z) | (f32_to_bf16(f0.w) << 16);
            p.z = f32_to_bf16(f1.x) | (f32_to_bf16(f1.y) << 16);
            p.w = f32_to_bf16(f1.z) | (f32_to_bf16(f1.w) << 16);
        }
        unsigned byte = (unsigned)(row * 256 + cc * 16);
        byte ^= (unsigned)((row & 7) << 4);
        *(uint4*)(ldsA + byte) = p;
    }
    __syncthreads();

    #pragma unroll
    for (int pass = 0; pass < 2; ++pass) {
        const bf16x8* Wf = pass ? Wf1 : Wf0;
        const float* bias = pass ? b1 : b0;
        uint2* Y = pass ? Rp : Sp;

        f32x4 acc[4][4];
        #pragma unroll
        for (int n = 0; n < 4; ++n) {
            float bv = bias[wc * 64 + n * 16 + l15];
            #pragma unroll
            for (int m = 0; m < 4; ++m) {
                acc[m][n][0] = bv; acc[m][n][1] = bv;
                acc[m][n][2] = bv; acc[m][n][3] = bv;
            }
        }
        #pragma unroll
        for (int ks = 0; ks < 4; ++ks) {
            const int kb = ks * 64 + lgp * 16;
            bf16x8 af[4], bfr[4];
            #pragma unroll
            for (int m = 0; m < 4; ++m) {
                int row = wr * 64 + m * 16 + l15;
                unsigned byte = ((unsigned)(row * 256 + kb)) ^ ((row & 7) << 4);
                af[m] = *(const bf16x8*)(ldsA + byte);
            }
            #pragma unroll
            for (int n = 0; n < 4; ++n)
                bfr[n] = Wf[((wc * 4 + n) * 4 + ks) * 64 + lane];
            #pragma unroll
            for (int m = 0; m < 4; ++m)
                #pragma unroll
                for (int n = 0; n < 4; ++n)
                    acc[m][n] = __builtin_amdgcn_mfma_f32_16x16x32_bf16(
                        af[m], bfr[n], acc[m][n], 0, 0, 0);
        }
        #pragma unroll
        for (int m = 0; m < 4; ++m)
            #pragma unroll
            for (int j = 0; j < 4; ++j) {
                int row = wr * 64 + m * 16 + lgp * 4 + j;
                size_t e = rowbase + row;
                if (e >= (size_t)M) continue;
                uint2 pk;
                pk.x = f32_to_bf16(acc[m][0][j]) | (f32_to_bf16(acc[m][1][j]) << 16);
                pk.y = f32_to_bf16(acc[m][2][j]) | (f32_to_bf16(acc[m][3][j]) << 16);
                Y[e * 32 + wc * 16 + l15] = pk;
            }
    }
}

// ---------- edge GEMM: EA/logits written at perm position ----------
// S/R gathers (bf16 uint2) are issued BEFORE stage-A/MFMA so their HBM
// latency hides under the staging loads and matrix math.
__global__ __launch_bounds__(256, 3) void edge_gemm(
    const float* __restrict__ X, const bf16x8* __restrict__ Wf,
    const float* __restrict__ bias,
    const float* __restrict__ attw, const float* __restrict__ attb,
    const int* __restrict__ senders, const int* __restrict__ receivers,
    const unsigned* __restrict__ jof,
    const uint2* __restrict__ Sp, const uint2* __restrict__ Rp,
    uint2* __restrict__ EAp, float* __restrict__ logits)
{
    __shared__ __align__(16) char ldsA[32768];
    __shared__ float sPart[128][4];
    __shared__ int sSnd[128], sRcv[128];
    __shared__ unsigned sJof[128];
    const int t = threadIdx.x;
    const int lane = t & 63;
    const int wid = t >> 6;
    const int wr = wid >> 1, wc = wid & 1;
    const int l15 = lane & 15, lgp = lane >> 4;
    const size_t rowbase = (size_t)blockIdx.x * 128;

    if (t < 128) {
        size_t e = rowbase + t;
        sSnd[t] = senders[e];
        sRcv[t] = receivers[e];
        sJof[t] = jof[e];
    }
    __syncthreads();

    // ---- prefetch S/R gathers into registers (use in tail) ----
    uint2 su[16], ru[16];
    #pragma unroll
    for (int m = 0; m < 4; ++m)
        #pragma unroll
        for (int j2 = 0; j2 < 4; ++j2) {
            int row = wr * 64 + m * 16 + lgp * 4 + j2;
            su[m * 4 + j2] = Sp[(size_t)sSnd[row] * 32 + wc * 16 + l15];
            ru[m * 4 + j2] = Rp[(size_t)sRcv[row] * 32 + wc * 16 + l15];
        }

    // ---- stage A (NE multiple of 128 -> no guards) ----
    #pragma unroll
    for (int i = 0; i < 8; ++i) {
        int c = i * 256 + t;
        int row = c >> 4, cc = c & 15;
        const float4* src = (const float4*)(X + (rowbase + row) * F + cc * 8);
        float4 f0 = src[0], f1 = src[1];
        uint4 p;
        p.x = f32_to_bf16(f0.x) | (f32_to_bf16(f0.y) << 16);
        p.y = f32_to_bf16(f0.z) | (f32_to_bf16(f0.w) << 16);
        p.z = f32_to_bf16(f1.x) | (f32_to_bf16(f1.y) << 16);
        p.w = f32_to_bf16(f1.z) | (f32_to_bf16(f1.w) << 16);
        unsigned byte = (unsigned)(row * 256 + cc * 16);
        byte ^= (unsigned)((row & 7) << 4);
        *(uint4*)(ldsA + byte) = p;
    }

    f32x4 acc[4][4];
    #pragma unroll
    for (int n = 0; n < 4; ++n) {
        float bv = bias[wc * 64 + n * 16 + l15];
        #pragma unroll
        for (int m = 0; m < 4; ++m) {
            acc[m][n][0] = bv; acc[m][n][1] = bv;
            acc[m][n][2] = bv; acc[m][n][3] = bv;
        }
    }
    __syncthreads();

    #pragma unroll
    for (int ks = 0; ks < 4; ++ks) {
        const int kb = ks * 64 + lgp * 16;
        bf16x8 af[4], bfr[4];
        #pragma unroll
        for (int m = 0; m < 4; ++m) {
            int row = wr * 64 + m * 16 + l15;
            unsigned byte = ((unsigned)(row * 256 + kb)) ^ ((row & 7) << 4);
            af[m] = *(const bf16x8*)(ldsA + byte);
        }
        #pragma unroll
        for (int n = 0; n < 4; ++n)
            bfr[n] = Wf[((wc * 4 + n) * 4 + ks) * 64 + lane];
        #pragma unroll
        for (int m = 0; m < 4; ++m)
            #pragma unroll
            for (int n = 0; n < 4; ++n)
                acc[m][n] = __builtin_amdgcn_mfma_f32_16x16x32_bf16(
                    af[m], bfr[n], acc[m][n], 0, 0, 0);
    }

    const float aw0 = attw[l15];
    const float aw1 = attw[l15 + 16];
    const float ab0 = attb[0];
    #pragma unroll
    for (int m = 0; m < 4; ++m) {
        #pragma unroll
        for (int j2 = 0; j2 < 4; ++j2) {
            int row = wr * 64 + m * 16 + lgp * 4 + j2;
            unsigned jj = sJof[row];
            uint2 sv = su[m * 4 + j2];
            uint2 rv = ru[m * 4 + j2];
            float ea0 = acc[m][0][j2] + bf16lo_to_f32(sv.x);
            float ea1 = acc[m][1][j2] + bf16hi_to_f32(sv.x);
            float ea2 = acc[m][2][j2] + bf16lo_to_f32(sv.y);
            float ea3 = acc[m][3][j2] + bf16hi_to_f32(sv.y);
            uint2 pk;
            pk.x = f32_to_bf16(ea0) | (f32_to_bf16(ea1) << 16);
            pk.y = f32_to_bf16(ea2) | (f32_to_bf16(ea3) << 16);
            EAp[(size_t)jj * 32 + wc * 16 + l15] = pk;
            float p0 = mish_f(ea0 + bf16lo_to_f32(rv.x)) * aw0
                     + mish_f(ea1 + bf16hi_to_f32(rv.x)) * aw1;
            float p1 = mish_f(ea2 + bf16lo_to_f32(rv.y)) * aw0
                     + mish_f(ea3 + bf16hi_to_f32(rv.y)) * aw1;
            p0 += __shfl_xor(p0, 1); p1 += __shfl_xor(p1, 1);
            p0 += __shfl_xor(p0, 2); p1 += __shfl_xor(p1, 2);
            p0 += __shfl_xor(p0, 4); p1 += __shfl_xor(p1, 4);
            p0 += __shfl_xor(p0, 8); p1 += __shfl_xor(p1, 8);
            if (l15 == 0) {
                sPart[row][wc * 2 + 0] = p0 + ab0;
                sPart[row][wc * 2 + 1] = p1 + ab0;
            }
        }
    }
    __syncthreads();
    if (t < 128) {
        unsigned jj = sJof[t];
        float4 lg;
        lg.x = sPart[t][0];
        lg.y = sPart[t][1];
        lg.z = sPart[t][2];
        lg.w = sPart[t][3];
        ((float4*)logits)[jj] = lg;
    }
}

// ---------- fused segment softmax + aggregate (one wave per receiver) ----------
// EA/logits are perm-ordered -> purely sequential segment reads.
__global__ __launch_bounds__(256) void agg_kernel(
    const unsigned* __restrict__ rowptr,
    const float* __restrict__ logits, const unsigned* __restrict__ EA,
    float* __restrict__ out)
{
    const int lane = threadIdx.x & 63;
    const int r = blockIdx.x * 4 + (threadIdx.x >> 6);
    if (r >= NN) return;
    const unsigned start = rowptr[r], end = rowptr[r + 1];
    if (start == end) {
        ((float2*)(out + (size_t)r * HD))[lane] = make_float2(0.f, 0.f);
        return;
    }

    // fragment-permuted EA: uint at index `lane` holds cols c0, c0+16
    const int h  = (lane >> 5) * 2 + (lane & 1);
    const int c0 = (lane >> 5) * 64 + (lane & 1) * 32 + ((lane >> 1) & 15);
    const float NEGBIG = -3.402823466e+38f;

    float4 mx = make_float4(NEGBIG, NEGBIG, NEGBIG, NEGBIG);
    for (unsigned j = start + lane; j < end; j += 64) {
        float4 lg = ((const float4*)logits)[j];
        mx.x = fmaxf(mx.x, lg.x); mx.y = fmaxf(mx.y, lg.y);
        mx.z = fmaxf(mx.z, lg.z); mx.w = fmaxf(mx.w, lg.w);
    }
    #pragma unroll
    for (int o = 1; o < 64; o <<= 1) {
        mx.x = fmaxf(mx.x, __shfl_xor(mx.x, o));
        mx.y = fmaxf(mx.y, __shfl_xor(mx.y, o));
        mx.z = fmaxf(mx.z, __shfl_xor(mx.z, o));
        mx.w = fmaxf(mx.w, __shfl_xor(mx.w, o));
    }
    float4 sm = make_float4(0.f, 0.f, 0.f, 0.f);
    for (unsigned j = start + lane; j < end; j += 64) {
        float4 lg = ((const float4*)logits)[j];
        sm.x += __expf(lg.x - mx.x); sm.y += __expf(lg.y - mx.y);
        sm.z += __expf(lg.z - mx.z); sm.w += __expf(lg.w - mx.w);
    }
    #pragma unroll
    for (int o = 1; o < 64; o <<= 1) {
        sm.x += __shfl_xor(sm.x, o);
        sm.y += __shfl_xor(sm.y, o);
        sm.z += __shfl_xor(sm.z, o);
        sm.w += __shfl_xor(sm.w, o);
    }
    const float mh = (h == 0) ? mx.x : (h == 1) ? mx.y : (h == 2) ? mx.z : mx.w;
    const float sh = (h == 0) ? sm.x : (h == 1) ? sm.y : (h == 2) ? sm.z : sm.w;
    const float rd = 1.f / sh;

    float2 acc = make_float2(0.f, 0.f);
    for (unsigned j = start; j < end; ++j) {
        float lg = logits[(size_t)j * 4 + h];
        float c = __expf(lg - mh) * rd;
        unsigned p = EA[(size_t)j * 64 + lane];
        acc.x += c * bf16lo_to_f32(p);
        acc.y += c * bf16hi_to_f32(p);
    }
    out[(size_t)r * HD + c0]      = acc.x;
    out[(size_t)r * HD + c0 + 16] = acc.y;
}

// ---------- host ----------
extern "C" void kernel_launch(void* const* d_in, const int* in_sizes, int n_in,
                              void* d_out, int out_size, void* d_ws, size_t ws_size,
                              hipStream_t stream) {
    const float* nodes = (const float*)d_in[0];
    const float* edges = (const float*)d_in[1];
    const float* Ws_k  = (const float*)d_in[2];
    const float* Ws_b  = (const float*)d_in[3];
    const float* Wr_k  = (const float*)d_in[4];
    const float* Wr_b  = (const float*)d_in[5];
    const float* We_k  = (const float*)d_in[6];
    const float* We_b  = (const float*)d_in[7];
    const float* attw  = (const float*)d_in[8];
    const float* attb  = (const float*)d_in[9];
    const int* senders   = (const int*)d_in[10];
    const int* receivers = (const int*)d_in[11];
    float* out = (float*)d_out;

    char* ws = (char*)d_ws;
    const size_t CNT_OFF  = 0;            // 200,000
    const size_t CNT2_OFF = 200000;       // 200,000
    const size_t RP_OFF   = 400000;       // 200,004
    const size_t JOF_OFF  = 700000;       // 3,200,000 -> ends 3,900,000
    const size_t WF_OFF   = 3900000;      // 98,304    -> ends 3,998,304
    const size_t SP_OFF   = 4000000;      // 12,800,000 (bf16) -> 16.8e6
    const size_t RPP_OFF  = 16800000;     // 12,800,000 -> 29.6e6
    const size_t LG_OFF   = 29600000;     // 12,800,000 -> 42.4e6
    const size_t EA_OFF   = 42400000;     // 204,800,000 -> 247.2e6

    unsigned* cnt    = (unsigned*)(ws + CNT_OFF);
    unsigned* cnt2   = (unsigned*)(ws + CNT2_OFF);
    unsigned* rowptr = (unsigned*)(ws + RP_OFF);
    unsigned* jof    = (unsigned*)(ws + JOF_OFF);
    uint4*    Wf     = (uint4*)(ws + WF_OFF);
    uint2*    Sp     = (uint2*)(ws + SP_OFF);
    uint2*    Rp     = (uint2*)(ws + RPP_OFF);
    float*    logits = (float*)(ws + LG_OFF);
    unsigned* EA     = (unsigned*)(ws + EA_OFF);
    (void)ws_size;

    // weights -> bf16 fragment order (Ws, Wr, We)
    prep_w<<<3, 256, 0, stream>>>(Ws_k, Wr_k, We_k, Wf);

    // CSR build (rowptr + inverse perm map jof)
    hipMemsetAsync(ws + CNT_OFF, 0, 400000, stream);   // cnt + cnt2
    hist_kernel<<<(NE + 255) / 256, 256, 0, stream>>>(receivers, cnt);
    scan_kernel<<<1, 1024, 0, stream>>>(cnt, rowptr);
    scatter_kernel<<<(NE + 255) / 256, 256, 0, stream>>>(receivers, rowptr, cnt2, jof);

    // both node projections (bf16 fragment-packed output)
    proj_both<<<(NN + 127) / 128, 256, 0, stream>>>(
        nodes, (const bf16x8*)Wf, (const bf16x8*)(Wf + 2048),
        Ws_b, Wr_b, NN, Sp, Rp);

    // edge GEMM: EA + logits, written at perm positions
    edge_gemm<<<NE / 128, 256, 0, stream>>>(
        edges, (const bf16x8*)(Wf + 4096), We_b,
        attw, attb, senders, receivers, jof, Sp, Rp,
        (uint2*)EA, logits);

    // fused segment softmax + aggregation (sequential segment streams)
    agg_kernel<<<(NN + 3) / 4, 256, 0, stream>>>(rowptr, logits, EA, out);
}

// Round 8
// 503.101 us; speedup vs baseline: 1.1344x; 1.1344x over previous
//
#include <hip/hip_runtime.h>
#include <hip/hip_bf16.h>

#define NN 50000
#define NE 800000
#define F 128     // input feature dim (= K)
#define HD 128    // output dim = H*DH (= N)
#define H 4

typedef __attribute__((ext_vector_type(4))) float f32x4;
typedef __attribute__((ext_vector_type(8))) __bf16 bf16x8;

// ---------- helpers ----------

// mish(x) = x * tanh(softplus(x)) = x * (u-1)/(u+1), u = (1+e^x)^2
__device__ __forceinline__ float mish_f(float x) {
    if (x > 30.f) return x;
    float t = __expf(x);
    float u = 1.f + t;
    u = u * u;
    return x * (u - 1.f) * __builtin_amdgcn_rcpf(u + 1.f);
}

__device__ __forceinline__ unsigned f32_to_bf16(float x) {
    unsigned u = __float_as_uint(x);
    u += 0x7FFFu + ((u >> 16) & 1u);
    return u >> 16;
}
__device__ __forceinline__ float bf16lo_to_f32(unsigned p) {
    return __uint_as_float((p & 0xFFFFu) << 16);
}
__device__ __forceinline__ float bf16hi_to_f32(unsigned p) {
    return __uint_as_float(p & 0xFFFF0000u);
}

// ---------- prep: W f32[128k x 128n] -> bf16 fragment-ordered ----------
__global__ __launch_bounds__(256) void prep_w(
    const float* __restrict__ W0, const float* __restrict__ W1,
    const float* __restrict__ W2, uint4* __restrict__ O)
{
    int b = blockIdx.x;
    const float* W = (b == 0) ? W0 : (b == 1) ? W1 : W2;
    uint4* out = O + b * 2048;
    for (int c = threadIdx.x; c < 2048; c += 256) {
        int fn = c >> 8, ks = (c >> 6) & 3, lane = c & 63;
        int lgp = lane >> 4, l15 = lane & 15;
        int col = fn * 16 + l15, k0 = ks * 32 + lgp * 8;
        unsigned u[4];
        #pragma unroll
        for (int i = 0; i < 4; ++i) {
            float a = W[(k0 + 2 * i) * 128 + col];
            float bb = W[(k0 + 2 * i + 1) * 128 + col];
            u[i] = f32_to_bf16(a) | (f32_to_bf16(bb) << 16);
        }
        out[c] = make_uint4(u[0], u[1], u[2], u[3]);
    }
}

// ---------- CSR build ----------
__global__ __launch_bounds__(256) void hist_kernel(
    const int* __restrict__ receivers, unsigned* __restrict__ cnt)
{
    int i = blockIdx.x * 256 + threadIdx.x;
    if (i < NE) atomicAdd(&cnt[receivers[i]], 1u);
}

__global__ __launch_bounds__(1024) void scan_kernel(
    const unsigned* __restrict__ cnt, unsigned* __restrict__ rowptr)
{
    __shared__ unsigned part[1024];
    const int t = threadIdx.x;
    const int C = (NN + 1023) / 1024;
    int base = t * C;
    unsigned s = 0;
    for (int i = 0; i < C; ++i) {
        int idx = base + i;
        if (idx < NN) s += cnt[idx];
    }
    part[t] = s;
    __syncthreads();
    for (int off = 1; off < 1024; off <<= 1) {
        unsigned v = (t >= off) ? part[t - off] : 0u;
        __syncthreads();
        if (t >= off) part[t] += v;
        __syncthreads();
    }
    unsigned run = part[t] - s;
    for (int i = 0; i < C; ++i) {
        int idx = base + i;
        if (idx < NN) { rowptr[idx] = run; run += cnt[idx]; }
    }
    if (t == 1023) rowptr[NN] = run;
}

// scatter + inverse map jof: edge e lands at perm position jof[e]
__global__ __launch_bounds__(256) void scatter_kernel(
    const int* __restrict__ receivers, const unsigned* __restrict__ rowptr,
    unsigned* __restrict__ cnt2, unsigned* __restrict__ jof)
{
    int i = blockIdx.x * 256 + threadIdx.x;
    if (i >= NE) return;
    int r = receivers[i];
    unsigned pos = rowptr[r] + atomicAdd(&cnt2[r], 1u);
    jof[i] = pos;
}

// ---------- both node projections in one kernel ----------
// Sp/Rp layout (bf16, head-interleaved): node row = 64 uints (256 B);
// uint k = l15*4 + h holds cols (32h + l15, 32h + 16 + l15) as 2 bf16.
// -> one uint4 gather at idx e*16 + l15 yields all 8 col-fragments.
__global__ __launch_bounds__(256, 4) void proj_both(
    const float* __restrict__ X,
    const bf16x8* __restrict__ Wf0, const bf16x8* __restrict__ Wf1,
    const float* __restrict__ b0, const float* __restrict__ b1,
    int M, uint2* __restrict__ Sp, uint2* __restrict__ Rp)
{
    __shared__ __align__(16) char ldsA[32768];
    const int t = threadIdx.x;
    const int lane = t & 63;
    const int wid = t >> 6;
    const int wr = wid >> 1, wc = wid & 1;
    const int l15 = lane & 15, lgp = lane >> 4;
    const size_t rowbase = (size_t)blockIdx.x * 128;

    #pragma unroll
    for (int i = 0; i < 8; ++i) {
        int c = i * 256 + t;
        int row = c >> 4, cc = c & 15;
        size_t e = rowbase + row;
        uint4 p = make_uint4(0, 0, 0, 0);
        if (e < (size_t)M) {
            const float4* src = (const float4*)(X + e * F + cc * 8);
            float4 f0 = src[0], f1 = src[1];
            p.x = f32_to_bf16(f0.x) | (f32_to_bf16(f0.y) << 16);
            p.y = f32_to_bf16(f0.z) | (f32_to_bf16(f0.w) << 16);
            p.z = f32_to_bf16(f1.x) | (f32_to_bf16(f1.y) << 16);
            p.w = f32_to_bf16(f1.z) | (f32_to_bf16(f1.w) << 16);
        }
        unsigned byte = (unsigned)(row * 256 + cc * 16);
        byte ^= (unsigned)((row & 7) << 4);
        *(uint4*)(ldsA + byte) = p;
    }
    __syncthreads();

    #pragma unroll
    for (int pass = 0; pass < 2; ++pass) {
        const bf16x8* Wf = pass ? Wf1 : Wf0;
        const float* bias = pass ? b1 : b0;
        uint2* Y = pass ? Rp : Sp;

        f32x4 acc[4][4];
        #pragma unroll
        for (int n = 0; n < 4; ++n) {
            float bv = bias[wc * 64 + n * 16 + l15];
            #pragma unroll
            for (int m = 0; m < 4; ++m) {
                acc[m][n][0] = bv; acc[m][n][1] = bv;
                acc[m][n][2] = bv; acc[m][n][3] = bv;
            }
        }
        #pragma unroll
        for (int ks = 0; ks < 4; ++ks) {
            const int kb = ks * 64 + lgp * 16;
            bf16x8 af[4], bfr[4];
            #pragma unroll
            for (int m = 0; m < 4; ++m) {
                int row = wr * 64 + m * 16 + l15;
                unsigned byte = ((unsigned)(row * 256 + kb)) ^ ((row & 7) << 4);
                af[m] = *(const bf16x8*)(ldsA + byte);
            }
            #pragma unroll
            for (int n = 0; n < 4; ++n)
                bfr[n] = Wf[((wc * 4 + n) * 4 + ks) * 64 + lane];
            #pragma unroll
            for (int m = 0; m < 4; ++m)
                #pragma unroll
                for (int n = 0; n < 4; ++n)
                    acc[m][n] = __builtin_amdgcn_mfma_f32_16x16x32_bf16(
                        af[m], bfr[n], acc[m][n], 0, 0, 0);
        }
        // store: this thread's cols are heads wc*2 + {0,1}, col-class l15
        #pragma unroll
        for (int m = 0; m < 4; ++m)
            #pragma unroll
            for (int j = 0; j < 4; ++j) {
                int row = wr * 64 + m * 16 + lgp * 4 + j;
                size_t e = rowbase + row;
                if (e >= (size_t)M) continue;
                uint2 pk;
                pk.x = f32_to_bf16(acc[m][0][j]) | (f32_to_bf16(acc[m][1][j]) << 16);
                pk.y = f32_to_bf16(acc[m][2][j]) | (f32_to_bf16(acc[m][3][j]) << 16);
                Y[e * 32 + l15 * 2 + wc] = pk;   // uints k = l15*4 + wc*2 + {0,1}
            }
    }
}

// ---------- edge GEMM: BM=64, high-occupancy ----------
// 4 waves/block, wave w owns rows w*16..w*16+15 across all 128 cols.
// EA row layout (bf16): uint k = l15*4 + h holds cols (32h+l15, 32h+16+l15).
__global__ __launch_bounds__(256, 6) void edge_gemm(
    const float* __restrict__ X, const bf16x8* __restrict__ Wf,
    const float* __restrict__ bias,
    const float* __restrict__ attw, const float* __restrict__ attb,
    const int* __restrict__ senders, const int* __restrict__ receivers,
    const unsigned* __restrict__ jof,
    const uint4* __restrict__ Sp4, const uint4* __restrict__ Rp4,
    uint4* __restrict__ EAp, float* __restrict__ logits)
{
    __shared__ __align__(16) char ldsA[16384];
    const int t = threadIdx.x;
    const int lane = t & 63;
    const int wid = t >> 6;
    const int l15 = lane & 15, lgp = lane >> 4;
    const size_t rowbase = (size_t)blockIdx.x * 64;

    // ---- stage A: 64 edge rows -> bf16, XOR-swizzled (16 KB) ----
    #pragma unroll
    for (int i = 0; i < 4; ++i) {
        int c = i * 256 + t;
        int row = c >> 4, cc = c & 15;
        const float4* src = (const float4*)(X + (rowbase + row) * F + cc * 8);
        float4 f0 = src[0], f1 = src[1];
        uint4 p;
        p.x = f32_to_bf16(f0.x) | (f32_to_bf16(f0.y) << 16);
        p.y = f32_to_bf16(f0.z) | (f32_to_bf16(f0.w) << 16);
        p.z = f32_to_bf16(f1.x) | (f32_to_bf16(f1.y) << 16);
        p.w = f32_to_bf16(f1.z) | (f32_to_bf16(f1.w) << 16);
        unsigned byte = (unsigned)(row * 256 + cc * 16);
        byte ^= (unsigned)((row & 7) << 4);
        *(uint4*)(ldsA + byte) = p;
    }

    f32x4 acc[8];
    #pragma unroll
    for (int n = 0; n < 8; ++n) {
        float bv = bias[n * 16 + l15];
        acc[n][0] = bv; acc[n][1] = bv; acc[n][2] = bv; acc[n][3] = bv;
    }
    __syncthreads();

    // ---- MFMA: A from LDS, B straight from L2-resident fragment buffer ----
    #pragma unroll
    for (int ks = 0; ks < 4; ++ks) {
        int arow = wid * 16 + l15;
        unsigned abyte = ((unsigned)(arow * 256 + ks * 64 + lgp * 16))
                         ^ ((arow & 7) << 4);
        bf16x8 af = *(const bf16x8*)(ldsA + abyte);
        #pragma unroll
        for (int n = 0; n < 8; ++n) {
            bf16x8 bfr = Wf[(n * 4 + ks) * 64 + lane];
            acc[n] = __builtin_amdgcn_mfma_f32_16x16x32_bf16(af, bfr, acc[n], 0, 0, 0);
        }
    }

    // ---- tail: 4 rows per thread (row = wid*16 + lgp*4 + j) ----
    const float aw0 = attw[l15];
    const float aw1 = attw[l15 + 16];
    const float ab0 = attb[0];
    #pragma unroll
    for (int j = 0; j < 4; ++j) {
        int row = wid * 16 + lgp * 4 + j;
        size_t e = rowbase + row;
        int snd = senders[e];          // 16-lane broadcast loads
        int rcv = receivers[e];
        unsigned jj = jof[e];
        uint4 sv = Sp4[(size_t)snd * 16 + l15];
        uint4 rv = Rp4[(size_t)rcv * 16 + l15];
        unsigned uo[4];
        float q[4];
        #pragma unroll
        for (int h = 0; h < 4; ++h) {
            unsigned sp = (h == 0) ? sv.x : (h == 1) ? sv.y : (h == 2) ? sv.z : sv.w;
            unsigned rp = (h == 0) ? rv.x : (h == 1) ? rv.y : (h == 2) ? rv.z : rv.w;
            float elo = acc[2 * h][j]     + bf16lo_to_f32(sp);
            float ehi = acc[2 * h + 1][j] + bf16hi_to_f32(sp);
            uo[h] = f32_to_bf16(elo) | (f32_to_bf16(ehi) << 16);
            q[h] = mish_f(elo + bf16lo_to_f32(rp)) * aw0
                 + mish_f(ehi + bf16hi_to_f32(rp)) * aw1;
        }
        EAp[(size_t)jj * 16 + l15] = make_uint4(uo[0], uo[1], uo[2], uo[3]);
        #pragma unroll
        for (int o = 1; o < 16; o <<= 1) {
            q[0] += __shfl_xor(q[0], o);
            q[1] += __shfl_xor(q[1], o);
            q[2] += __shfl_xor(q[2], o);
            q[3] += __shfl_xor(q[3], o);
        }
        if (l15 == 0)
            ((float4*)logits)[jj] =
                make_float4(q[0] + ab0, q[1] + ab0, q[2] + ab0, q[3] + ab0);
    }
}

// ---------- fused segment softmax + aggregate (one wave per receiver) ----------
// EA/logits are perm-ordered -> purely sequential segment reads.
__global__ __launch_bounds__(256) void agg_kernel(
    const unsigned* __restrict__ rowptr,
    const float* __restrict__ logits, const unsigned* __restrict__ EA,
    float* __restrict__ out)
{
    const int lane = threadIdx.x & 63;
    const int r = blockIdx.x * 4 + (threadIdx.x >> 6);
    if (r >= NN) return;
    const unsigned start = rowptr[r], end = rowptr[r + 1];
    if (start == end) {
        ((float2*)(out + (size_t)r * HD))[lane] = make_float2(0.f, 0.f);
        return;
    }

    // EA uint k = lane: l15c = lane>>2, h = lane&3, cols (32h+l15c, +16)
    const int h  = lane & 3;
    const int c0 = 32 * h + (lane >> 2);
    const float NEGBIG = -3.402823466e+38f;

    float4 mx = make_float4(NEGBIG, NEGBIG, NEGBIG, NEGBIG);
    for (unsigned j = start + lane; j < end; j += 64) {
        float4 lg = ((const float4*)logits)[j];
        mx.x = fmaxf(mx.x, lg.x); mx.y = fmaxf(mx.y, lg.y);
        mx.z = fmaxf(mx.z, lg.z); mx.w = fmaxf(mx.w, lg.w);
    }
    #pragma unroll
    for (int o = 1; o < 64; o <<= 1) {
        mx.x = fmaxf(mx.x, __shfl_xor(mx.x, o));
        mx.y = fmaxf(mx.y, __shfl_xor(mx.y, o));
        mx.z = fmaxf(mx.z, __shfl_xor(mx.z, o));
        mx.w = fmaxf(mx.w, __shfl_xor(mx.w, o));
    }
    float4 sm = make_float4(0.f, 0.f, 0.f, 0.f);
    for (unsigned j = start + lane; j < end; j += 64) {
        float4 lg = ((const float4*)logits)[j];
        sm.x += __expf(lg.x - mx.x); sm.y += __expf(lg.y - mx.y);
        sm.z += __expf(lg.z - mx.z); sm.w += __expf(lg.w - mx.w);
    }
    #pragma unroll
    for (int o = 1; o < 64; o <<= 1) {
        sm.x += __shfl_xor(sm.x, o);
        sm.y += __shfl_xor(sm.y, o);
        sm.z += __shfl_xor(sm.z, o);
        sm.w += __shfl_xor(sm.w, o);
    }
    const float mh = (h == 0) ? mx.x : (h == 1) ? mx.y : (h == 2) ? mx.z : mx.w;
    const float sh = (h == 0) ? sm.x : (h == 1) ? sm.y : (h == 2) ? sm.z : sm.w;
    const float rd = 1.f / sh;

    float2 acc = make_float2(0.f, 0.f);
    for (unsigned j = start; j < end; ++j) {
        float lg = logits[(size_t)j * 4 + h];
        float c = __expf(lg - mh) * rd;
        unsigned p = EA[(size_t)j * 64 + lane];
        acc.x += c * bf16lo_to_f32(p);
        acc.y += c * bf16hi_to_f32(p);
    }
    out[(size_t)r * HD + c0]      = acc.x;
    out[(size_t)r * HD + c0 + 16] = acc.y;
}

// ---------- host ----------
extern "C" void kernel_launch(void* const* d_in, const int* in_sizes, int n_in,
                              void* d_out, int out_size, void* d_ws, size_t ws_size,
                              hipStream_t stream) {
    const float* nodes = (const float*)d_in[0];
    const float* edges = (const float*)d_in[1];
    const float* Ws_k  = (const float*)d_in[2];
    const float* Ws_b  = (const float*)d_in[3];
    const float* Wr_k  = (const float*)d_in[4];
    const float* Wr_b  = (const float*)d_in[5];
    const float* We_k  = (const float*)d_in[6];
    const float* We_b  = (const float*)d_in[7];
    const float* attw  = (const float*)d_in[8];
    const float* attb  = (const float*)d_in[9];
    const int* senders   = (const int*)d_in[10];
    const int* receivers = (const int*)d_in[11];
    float* out = (float*)d_out;

    char* ws = (char*)d_ws;
    const size_t CNT_OFF  = 0;            // 200,000
    const size_t CNT2_OFF = 200000;       // 200,000
    const size_t RP_OFF   = 400000;       // 200,004
    const size_t JOF_OFF  = 700000;       // 3,200,000 -> ends 3,900,000
    const size_t WF_OFF   = 3900000;      // 98,304    -> ends 3,998,304
    const size_t SP_OFF   = 4000000;      // 12,800,000 (bf16) -> 16.8e6
    const size_t RPP_OFF  = 16800000;     // 12,800,000 -> 29.6e6
    const size_t LG_OFF   = 29600000;     // 12,800,000 -> 42.4e6
    const size_t EA_OFF   = 42400000;     // 204,800,000 -> 247.2e6

    unsigned* cnt    = (unsigned*)(ws + CNT_OFF);
    unsigned* cnt2   = (unsigned*)(ws + CNT2_OFF);
    unsigned* rowptr = (unsigned*)(ws + RP_OFF);
    unsigned* jof    = (unsigned*)(ws + JOF_OFF);
    uint4*    Wf     = (uint4*)(ws + WF_OFF);
    uint2*    Sp     = (uint2*)(ws + SP_OFF);
    uint2*    Rp     = (uint2*)(ws + RPP_OFF);
    float*    logits = (float*)(ws + LG_OFF);
    unsigned* EA     = (unsigned*)(ws + EA_OFF);
    (void)ws_size;

    // weights -> bf16 fragment order (Ws, Wr, We)
    prep_w<<<3, 256, 0, stream>>>(Ws_k, Wr_k, We_k, Wf);

    // CSR build (rowptr + inverse perm map jof)
    hipMemsetAsync(ws + CNT_OFF, 0, 400000, stream);   // cnt + cnt2
    hist_kernel<<<(NE + 255) / 256, 256, 0, stream>>>(receivers, cnt);
    scan_kernel<<<1, 1024, 0, stream>>>(cnt, rowptr);
    scatter_kernel<<<(NE + 255) / 256, 256, 0, stream>>>(receivers, rowptr, cnt2, jof);

    // both node projections (bf16 head-interleaved packed output)
    proj_both<<<(NN + 127) / 128, 256, 0, stream>>>(
        nodes, (const bf16x8*)Wf, (const bf16x8*)(Wf + 2048),
        Ws_b, Wr_b, NN, Sp, Rp);

    // edge GEMM: EA + logits, written at perm positions
    edge_gemm<<<NE / 64, 256, 0, stream>>>(
        edges, (const bf16x8*)(Wf + 4096), We_b,
        attw, attb, senders, receivers, jof,
        (const uint4*)Sp, (const uint4*)Rp,
        (uint4*)EA, logits);

    // fused segment softmax + aggregation (sequential segment streams)
    agg_kernel<<<(NN + 3) / 4, 256, 0, stream>>>(rowptr, logits, EA, out);
}

// Round 9
// 489.396 us; speedup vs baseline: 1.1661x; 1.0280x over previous
//
#include <hip/hip_runtime.h>
#include <hip/hip_bf16.h>

#define NN 50000
#define NE 800000
#define F 128     // input feature dim (= K)
#define HD 128    // output dim = H*DH (= N)
#define H 4

typedef __attribute__((ext_vector_type(4))) float f32x4;
typedef __attribute__((ext_vector_type(8))) __bf16 bf16x8;

// ---------- helpers ----------

// mish(x) = x * tanh(softplus(x)) = x * (u-1)/(u+1), u = (1+e^x)^2
__device__ __forceinline__ float mish_f(float x) {
    if (x > 30.f) return x;
    float t = __expf(x);
    float u = 1.f + t;
    u = u * u;
    return x * (u - 1.f) * __builtin_amdgcn_rcpf(u + 1.f);
}

__device__ __forceinline__ unsigned f32_to_bf16(float x) {
    unsigned u = __float_as_uint(x);
    u += 0x7FFFu + ((u >> 16) & 1u);
    return u >> 16;
}
__device__ __forceinline__ float bf16lo_to_f32(unsigned p) {
    return __uint_as_float((p & 0xFFFFu) << 16);
}
__device__ __forceinline__ float bf16hi_to_f32(unsigned p) {
    return __uint_as_float(p & 0xFFFF0000u);
}

// ---------- prep: W f32[128k x 128n] -> bf16 fragment-ordered ----------
__global__ __launch_bounds__(256) void prep_w(
    const float* __restrict__ W0, const float* __restrict__ W1,
    const float* __restrict__ W2, uint4* __restrict__ O)
{
    int b = blockIdx.x;
    const float* W = (b == 0) ? W0 : (b == 1) ? W1 : W2;
    uint4* out = O + b * 2048;
    for (int c = threadIdx.x; c < 2048; c += 256) {
        int fn = c >> 8, ks = (c >> 6) & 3, lane = c & 63;
        int lgp = lane >> 4, l15 = lane & 15;
        int col = fn * 16 + l15, k0 = ks * 32 + lgp * 8;
        unsigned u[4];
        #pragma unroll
        for (int i = 0; i < 4; ++i) {
            float a = W[(k0 + 2 * i) * 128 + col];
            float bb = W[(k0 + 2 * i + 1) * 128 + col];
            u[i] = f32_to_bf16(a) | (f32_to_bf16(bb) << 16);
        }
        out[c] = make_uint4(u[0], u[1], u[2], u[3]);
    }
}

// ---------- CSR build ----------
__global__ __launch_bounds__(256) void hist_kernel(
    const int* __restrict__ receivers, unsigned* __restrict__ cnt)
{
    int i = blockIdx.x * 256 + threadIdx.x;
    if (i < NE) atomicAdd(&cnt[receivers[i]], 1u);
}

__global__ __launch_bounds__(1024) void scan_kernel(
    const unsigned* __restrict__ cnt, unsigned* __restrict__ rowptr)
{
    __shared__ unsigned part[1024];
    const int t = threadIdx.x;
    const int C = (NN + 1023) / 1024;
    int base = t * C;
    unsigned s = 0;
    for (int i = 0; i < C; ++i) {
        int idx = base + i;
        if (idx < NN) s += cnt[idx];
    }
    part[t] = s;
    __syncthreads();
    for (int off = 1; off < 1024; off <<= 1) {
        unsigned v = (t >= off) ? part[t - off] : 0u;
        __syncthreads();
        if (t >= off) part[t] += v;
        __syncthreads();
    }
    unsigned run = part[t] - s;
    for (int i = 0; i < C; ++i) {
        int idx = base + i;
        if (idx < NN) { rowptr[idx] = run; run += cnt[idx]; }
    }
    if (t == 1023) rowptr[NN] = run;
}

// scatter + inverse map jof: edge e lands at perm position jof[e]
__global__ __launch_bounds__(256) void scatter_kernel(
    const int* __restrict__ receivers, const unsigned* __restrict__ rowptr,
    unsigned* __restrict__ cnt2, unsigned* __restrict__ jof)
{
    int i = blockIdx.x * 256 + threadIdx.x;
    if (i >= NE) return;
    int r = receivers[i];
    unsigned pos = rowptr[r] + atomicAdd(&cnt2[r], 1u);
    jof[i] = pos;
}

// ---------- both node projections in one kernel ----------
// Sp/Rp layout (bf16, head-interleaved): node row = 64 uints (256 B);
// uint k = l15*4 + h holds cols (32h + l15, 32h + 16 + l15) as 2 bf16.
// -> one uint4 gather at idx e*16 + l15 yields all 8 col-fragments.
__global__ __launch_bounds__(256, 4) void proj_both(
    const float* __restrict__ X,
    const bf16x8* __restrict__ Wf0, const bf16x8* __restrict__ Wf1,
    const float* __restrict__ b0, const float* __restrict__ b1,
    int M, uint2* __restrict__ Sp, uint2* __restrict__ Rp)
{
    __shared__ __align__(16) char ldsA[32768];
    const int t = threadIdx.x;
    const int lane = t & 63;
    const int wid = t >> 6;
    const int wr = wid >> 1, wc = wid & 1;
    const int l15 = lane & 15, lgp = lane >> 4;
    const size_t rowbase = (size_t)blockIdx.x * 128;

    #pragma unroll
    for (int i = 0; i < 8; ++i) {
        int c = i * 256 + t;
        int row = c >> 4, cc = c & 15;
        size_t e = rowbase + row;
        uint4 p = make_uint4(0, 0, 0, 0);
        if (e < (size_t)M) {
            const float4* src = (const float4*)(X + e * F + cc * 8);
            float4 f0 = src[0], f1 = src[1];
            p.x = f32_to_bf16(f0.x) | (f32_to_bf16(f0.y) << 16);
            p.y = f32_to_bf16(f0.z) | (f32_to_bf16(f0.w) << 16);
            p.z = f32_to_bf16(f1.x) | (f32_to_bf16(f1.y) << 16);
            p.w = f32_to_bf16(f1.z) | (f32_to_bf16(f1.w) << 16);
        }
        unsigned byte = (unsigned)(row * 256 + cc * 16);
        byte ^= (unsigned)((row & 7) << 4);
        *(uint4*)(ldsA + byte) = p;
    }
    __syncthreads();

    #pragma unroll
    for (int pass = 0; pass < 2; ++pass) {
        const bf16x8* Wf = pass ? Wf1 : Wf0;
        const float* bias = pass ? b1 : b0;
        uint2* Y = pass ? Rp : Sp;

        f32x4 acc[4][4];
        #pragma unroll
        for (int n = 0; n < 4; ++n) {
            float bv = bias[wc * 64 + n * 16 + l15];
            #pragma unroll
            for (int m = 0; m < 4; ++m) {
                acc[m][n][0] = bv; acc[m][n][1] = bv;
                acc[m][n][2] = bv; acc[m][n][3] = bv;
            }
        }
        #pragma unroll
        for (int ks = 0; ks < 4; ++ks) {
            const int kb = ks * 64 + lgp * 16;
            bf16x8 af[4], bfr[4];
            #pragma unroll
            for (int m = 0; m < 4; ++m) {
                int row = wr * 64 + m * 16 + l15;
                unsigned byte = ((unsigned)(row * 256 + kb)) ^ ((row & 7) << 4);
                af[m] = *(const bf16x8*)(ldsA + byte);
            }
            #pragma unroll
            for (int n = 0; n < 4; ++n)
                bfr[n] = Wf[((wc * 4 + n) * 4 + ks) * 64 + lane];
            #pragma unroll
            for (int m = 0; m < 4; ++m)
                #pragma unroll
                for (int n = 0; n < 4; ++n)
                    acc[m][n] = __builtin_amdgcn_mfma_f32_16x16x32_bf16(
                        af[m], bfr[n], acc[m][n], 0, 0, 0);
        }
        // store: this thread's cols are heads wc*2 + {0,1}, col-class l15
        #pragma unroll
        for (int m = 0; m < 4; ++m)
            #pragma unroll
            for (int j = 0; j < 4; ++j) {
                int row = wr * 64 + m * 16 + lgp * 4 + j;
                size_t e = rowbase + row;
                if (e >= (size_t)M) continue;
                uint2 pk;
                pk.x = f32_to_bf16(acc[m][0][j]) | (f32_to_bf16(acc[m][1][j]) << 16);
                pk.y = f32_to_bf16(acc[m][2][j]) | (f32_to_bf16(acc[m][3][j]) << 16);
                Y[e * 32 + l15 * 2 + wc] = pk;   // uints k = l15*4 + wc*2 + {0,1}
            }
    }
}

// ---------- edge GEMM: BM=64, minimal tail ----------
// 4 waves/block, wave w owns rows w*16..w*16+15 across all 128 cols.
// EA row layout (bf16): uint k = l15*4 + h holds cols (32h+l15, 32h+16+l15).
// Tail: EA = acc + S[snd], pack, one uint4 store at perm position. Logit
// computation moved to agg (reads EA anyway).
__global__ __launch_bounds__(256, 6) void edge_gemm(
    const float* __restrict__ X, const bf16x8* __restrict__ Wf,
    const float* __restrict__ bias,
    const int* __restrict__ senders, const unsigned* __restrict__ jof,
    const uint4* __restrict__ Sp4, uint4* __restrict__ EAp)
{
    __shared__ __align__(16) char ldsA[16384];
    const int t = threadIdx.x;
    const int lane = t & 63;
    const int wid = t >> 6;
    const int l15 = lane & 15, lgp = lane >> 4;
    const size_t rowbase = (size_t)blockIdx.x * 64;

    // ---- stage A: 64 edge rows -> bf16, XOR-swizzled (16 KB) ----
    #pragma unroll
    for (int i = 0; i < 4; ++i) {
        int c = i * 256 + t;
        int row = c >> 4, cc = c & 15;
        const float4* src = (const float4*)(X + (rowbase + row) * F + cc * 8);
        float4 f0 = src[0], f1 = src[1];
        uint4 p;
        p.x = f32_to_bf16(f0.x) | (f32_to_bf16(f0.y) << 16);
        p.y = f32_to_bf16(f0.z) | (f32_to_bf16(f0.w) << 16);
        p.z = f32_to_bf16(f1.x) | (f32_to_bf16(f1.y) << 16);
        p.w = f32_to_bf16(f1.z) | (f32_to_bf16(f1.w) << 16);
        unsigned byte = (unsigned)(row * 256 + cc * 16);
        byte ^= (unsigned)((row & 7) << 4);
        *(uint4*)(ldsA + byte) = p;
    }

    f32x4 acc[8];
    #pragma unroll
    for (int n = 0; n < 8; ++n) {
        float bv = bias[n * 16 + l15];
        acc[n][0] = bv; acc[n][1] = bv; acc[n][2] = bv; acc[n][3] = bv;
    }
    __syncthreads();

    // ---- MFMA: A from LDS, B straight from L2-resident fragment buffer ----
    #pragma unroll
    for (int ks = 0; ks < 4; ++ks) {
        int arow = wid * 16 + l15;
        unsigned abyte = ((unsigned)(arow * 256 + ks * 64 + lgp * 16))
                         ^ ((arow & 7) << 4);
        bf16x8 af = *(const bf16x8*)(ldsA + abyte);
        #pragma unroll
        for (int n = 0; n < 8; ++n) {
            bf16x8 bfr = Wf[(n * 4 + ks) * 64 + lane];
            acc[n] = __builtin_amdgcn_mfma_f32_16x16x32_bf16(af, bfr, acc[n], 0, 0, 0);
        }
    }

    // ---- tail: 4 rows per thread (row = wid*16 + lgp*4 + j) ----
    #pragma unroll
    for (int j = 0; j < 4; ++j) {
        int row = wid * 16 + lgp * 4 + j;
        size_t e = rowbase + row;
        int snd = senders[e];          // 16-lane broadcast loads
        unsigned jj = jof[e];
        uint4 sv = Sp4[(size_t)snd * 16 + l15];
        unsigned uo[4];
        #pragma unroll
        for (int h = 0; h < 4; ++h) {
            unsigned sp = (h == 0) ? sv.x : (h == 1) ? sv.y : (h == 2) ? sv.z : sv.w;
            float elo = acc[2 * h][j]     + bf16lo_to_f32(sp);
            float ehi = acc[2 * h + 1][j] + bf16hi_to_f32(sp);
            uo[h] = f32_to_bf16(elo) | (f32_to_bf16(ehi) << 16);
        }
        EAp[(size_t)jj * 16 + l15] = make_uint4(uo[0], uo[1], uo[2], uo[3]);
    }
}

// ---------- fused logit + single-pass softmax + aggregate ----------
// One wave per receiver. Per edge row (sequential in perm order): recompute
// logit from bf16 EA + R[rcv] (4-step 16-lane shfl reduce per head), then
// max-free online softmax: w = exp(logit); acc += w*ea; den += w.
__global__ __launch_bounds__(256) void agg_kernel(
    const unsigned* __restrict__ rowptr,
    const uint4* __restrict__ Rp4,
    const float* __restrict__ attw, const float* __restrict__ attb,
    const unsigned* __restrict__ EA, float* __restrict__ out)
{
    const int lane = threadIdx.x & 63;
    const int r = blockIdx.x * 4 + (threadIdx.x >> 6);
    if (r >= NN) return;
    const unsigned start = rowptr[r], end = rowptr[r + 1];

    // EA uint k = lane: l15c = lane>>2, h = lane&3, cols (32h+l15c, +16)
    const int h    = lane & 3;
    const int l15c = lane >> 2;
    const int c0   = 32 * h + l15c;

    if (start == end) {
        out[(size_t)r * HD + c0]      = 0.f;
        out[(size_t)r * HD + c0 + 16] = 0.f;
        return;
    }

    uint4 rv4 = Rp4[(size_t)r * 16 + l15c];
    unsigned rp = (h == 0) ? rv4.x : (h == 1) ? rv4.y : (h == 2) ? rv4.z : rv4.w;
    const float rlo = bf16lo_to_f32(rp), rhi = bf16hi_to_f32(rp);
    const float aw0 = attw[l15c];
    const float aw1 = attw[l15c + 16];
    const float ab0 = attb[0];

    float accx = 0.f, accy = 0.f, den = 0.f;
    for (unsigned j = start; j < end; ++j) {
        unsigned p = EA[(size_t)j * 64 + lane];
        float elo = bf16lo_to_f32(p), ehi = bf16hi_to_f32(p);
        float t = mish_f(elo + rlo) * aw0 + mish_f(ehi + rhi) * aw1;
        // reduce across the 16 lanes sharing head h (lane bits 2..5)
        t += __shfl_xor(t, 4);
        t += __shfl_xor(t, 8);
        t += __shfl_xor(t, 16);
        t += __shfl_xor(t, 32);
        float w = __expf(t + ab0);
        den  += w;
        accx += w * elo;
        accy += w * ehi;
    }
    float rd = 1.f / den;
    out[(size_t)r * HD + c0]      = accx * rd;
    out[(size_t)r * HD + c0 + 16] = accy * rd;
}

// ---------- host ----------
extern "C" void kernel_launch(void* const* d_in, const int* in_sizes, int n_in,
                              void* d_out, int out_size, void* d_ws, size_t ws_size,
                              hipStream_t stream) {
    const float* nodes = (const float*)d_in[0];
    const float* edges = (const float*)d_in[1];
    const float* Ws_k  = (const float*)d_in[2];
    const float* Ws_b  = (const float*)d_in[3];
    const float* Wr_k  = (const float*)d_in[4];
    const float* Wr_b  = (const float*)d_in[5];
    const float* We_k  = (const float*)d_in[6];
    const float* We_b  = (const float*)d_in[7];
    const float* attw  = (const float*)d_in[8];
    const float* attb  = (const float*)d_in[9];
    const int* senders   = (const int*)d_in[10];
    const int* receivers = (const int*)d_in[11];
    float* out = (float*)d_out;

    char* ws = (char*)d_ws;
    const size_t CNT_OFF  = 0;            // 200,000
    const size_t CNT2_OFF = 200000;       // 200,000
    const size_t RP_OFF   = 400000;       // 200,004
    const size_t JOF_OFF  = 700000;       // 3,200,000 -> ends 3,900,000
    const size_t WF_OFF   = 3900000;      // 98,304    -> ends 3,998,304
    const size_t SP_OFF   = 4000000;      // 12,800,000 (bf16) -> 16.8e6
    const size_t RPP_OFF  = 16800000;     // 12,800,000 -> 29.6e6
    const size_t EA_OFF   = 29600000;     // 204,800,000 -> 234.4e6

    unsigned* cnt    = (unsigned*)(ws + CNT_OFF);
    unsigned* cnt2   = (unsigned*)(ws + CNT2_OFF);
    unsigned* rowptr = (unsigned*)(ws + RP_OFF);
    unsigned* jof    = (unsigned*)(ws + JOF_OFF);
    uint4*    Wf     = (uint4*)(ws + WF_OFF);
    uint2*    Sp     = (uint2*)(ws + SP_OFF);
    uint2*    Rp     = (uint2*)(ws + RPP_OFF);
    unsigned* EA     = (unsigned*)(ws + EA_OFF);
    (void)ws_size;

    // weights -> bf16 fragment order (Ws, Wr, We)
    prep_w<<<3, 256, 0, stream>>>(Ws_k, Wr_k, We_k, Wf);

    // CSR build (rowptr + inverse perm map jof)
    hipMemsetAsync(ws + CNT_OFF, 0, 400000, stream);   // cnt + cnt2
    hist_kernel<<<(NE + 255) / 256, 256, 0, stream>>>(receivers, cnt);
    scan_kernel<<<1, 1024, 0, stream>>>(cnt, rowptr);
    scatter_kernel<<<(NE + 255) / 256, 256, 0, stream>>>(receivers, rowptr, cnt2, jof);

    // both node projections (bf16 head-interleaved packed output)
    proj_both<<<(NN + 127) / 128, 256, 0, stream>>>(
        nodes, (const bf16x8*)Wf, (const bf16x8*)(Wf + 2048),
        Ws_b, Wr_b, NN, Sp, Rp);

    // edge GEMM: EA written at perm positions (no logits, no R gather)
    edge_gemm<<<NE / 64, 256, 0, stream>>>(
        edges, (const bf16x8*)(Wf + 4096), We_b,
        senders, jof, (const uint4*)Sp, (uint4*)EA);

    // fused logit + single-pass softmax + aggregation
    agg_kernel<<<(NN + 3) / 4, 256, 0, stream>>>(
        rowptr, (const uint4*)Rp, attw, attb, EA, out);
}

// Round 10
// 363.187 us; speedup vs baseline: 1.5714x; 1.3475x over previous
//
#include <hip/hip_runtime.h>
#include <hip/hip_bf16.h>

#define NN 50000
#define NE 800000
#define F 128     // input feature dim (= K)
#define HD 128    // output dim = H*DH (= N)
#define H 4

typedef __attribute__((ext_vector_type(4))) float f32x4;
typedef __attribute__((ext_vector_type(8))) __bf16 bf16x8;

// ---------- helpers ----------

// mish(x) = x * tanh(softplus(x)) = x * (u-1)/(u+1), u = (1+e^x)^2
__device__ __forceinline__ float mish_f(float x) {
    if (x > 30.f) return x;
    float t = __expf(x);
    float u = 1.f + t;
    u = u * u;
    return x * (u - 1.f) * __builtin_amdgcn_rcpf(u + 1.f);
}

__device__ __forceinline__ unsigned f32_to_bf16(float x) {
    unsigned u = __float_as_uint(x);
    u += 0x7FFFu + ((u >> 16) & 1u);
    return u >> 16;
}
__device__ __forceinline__ float bf16lo_to_f32(unsigned p) {
    return __uint_as_float((p & 0xFFFFu) << 16);
}
__device__ __forceinline__ float bf16hi_to_f32(unsigned p) {
    return __uint_as_float(p & 0xFFFF0000u);
}

// ---------- prep: W f32[128k x 128n] -> bf16 fragment-ordered ----------
__global__ __launch_bounds__(256) void prep_w(
    const float* __restrict__ W0, const float* __restrict__ W1,
    const float* __restrict__ W2, uint4* __restrict__ O)
{
    int b = blockIdx.x;
    const float* W = (b == 0) ? W0 : (b == 1) ? W1 : W2;
    uint4* out = O + b * 2048;
    for (int c = threadIdx.x; c < 2048; c += 256) {
        int fn = c >> 8, ks = (c >> 6) & 3, lane = c & 63;
        int lgp = lane >> 4, l15 = lane & 15;
        int col = fn * 16 + l15, k0 = ks * 32 + lgp * 8;
        unsigned u[4];
        #pragma unroll
        for (int i = 0; i < 4; ++i) {
            float a = W[(k0 + 2 * i) * 128 + col];
            float bb = W[(k0 + 2 * i + 1) * 128 + col];
            u[i] = f32_to_bf16(a) | (f32_to_bf16(bb) << 16);
        }
        out[c] = make_uint4(u[0], u[1], u[2], u[3]);
    }
}

// ---------- CSR build ----------
__global__ __launch_bounds__(256) void hist_kernel(
    const int* __restrict__ receivers, unsigned* __restrict__ cnt)
{
    int i = blockIdx.x * 256 + threadIdx.x;
    if (i < NE) atomicAdd(&cnt[receivers[i]], 1u);
}

// scan phase 1: per-block exclusive scan of 256 counts + block sum
__global__ __launch_bounds__(256) void scan1_kernel(
    const unsigned* __restrict__ cnt, unsigned* __restrict__ rowptr,
    unsigned* __restrict__ bsum)
{
    __shared__ unsigned sh[256];
    const int t = threadIdx.x;
    int i = blockIdx.x * 256 + t;
    unsigned c = (i < NN) ? cnt[i] : 0u;
    sh[t] = c;
    __syncthreads();
    unsigned incl = c;
    for (int off = 1; off < 256; off <<= 1) {
        unsigned v = (t >= off) ? sh[t - off] : 0u;
        __syncthreads();
        incl += v;
        sh[t] = incl;
        __syncthreads();
    }
    if (i < NN) rowptr[i] = incl - c;      // exclusive within block
    if (t == 255) bsum[blockIdx.x] = incl; // block total
}

// scan phase 2: single small block scans the 196 block sums
__global__ __launch_bounds__(256) void scan2_kernel(
    unsigned* __restrict__ bsum, unsigned* __restrict__ boff, int nb,
    unsigned* __restrict__ rowptr)
{
    __shared__ unsigned sh[256];
    const int t = threadIdx.x;
    unsigned c = (t < nb) ? bsum[t] : 0u;
    sh[t] = c;
    __syncthreads();
    unsigned incl = c;
    for (int off = 1; off < 256; off <<= 1) {
        unsigned v = (t >= off) ? sh[t - off] : 0u;
        __syncthreads();
        incl += v;
        sh[t] = incl;
        __syncthreads();
    }
    if (t < nb) boff[t] = incl - c;
    if (t == 0) rowptr[NN] = NE;
}

// scan phase 3: add block offsets
__global__ __launch_bounds__(256) void scan3_kernel(
    unsigned* __restrict__ rowptr, const unsigned* __restrict__ boff)
{
    int i = blockIdx.x * 256 + threadIdx.x;
    if (i < NN) rowptr[i] += boff[blockIdx.x];
}

// scatter + inverse map jof: edge e lands at perm position jof[e]
__global__ __launch_bounds__(256) void scatter_kernel(
    const int* __restrict__ receivers, const unsigned* __restrict__ rowptr,
    unsigned* __restrict__ cnt2, unsigned* __restrict__ jof)
{
    int i = blockIdx.x * 256 + threadIdx.x;
    if (i >= NE) return;
    int r = receivers[i];
    unsigned pos = rowptr[r] + atomicAdd(&cnt2[r], 1u);
    jof[i] = pos;
}

// ---------- both node projections in one kernel ----------
// Sp/Rp layout (bf16, head-interleaved): node row = 64 uints (256 B);
// uint k = l15*4 + h holds cols (32h + l15, 32h + 16 + l15) as 2 bf16.
// -> one uint4 gather at idx e*16 + l15 yields all 8 col-fragments.
__global__ __launch_bounds__(256, 4) void proj_both(
    const float* __restrict__ X,
    const bf16x8* __restrict__ Wf0, const bf16x8* __restrict__ Wf1,
    const float* __restrict__ b0, const float* __restrict__ b1,
    int M, uint2* __restrict__ Sp, uint2* __restrict__ Rp)
{
    __shared__ __align__(16) char ldsA[32768];
    const int t = threadIdx.x;
    const int lane = t & 63;
    const int wid = t >> 6;
    const int wr = wid >> 1, wc = wid & 1;
    const int l15 = lane & 15, lgp = lane >> 4;
    const size_t rowbase = (size_t)blockIdx.x * 128;

    #pragma unroll
    for (int i = 0; i < 8; ++i) {
        int c = i * 256 + t;
        int row = c >> 4, cc = c & 15;
        size_t e = rowbase + row;
        uint4 p = make_uint4(0, 0, 0, 0);
        if (e < (size_t)M) {
            const float4* src = (const float4*)(X + e * F + cc * 8);
            float4 f0 = src[0], f1 = src[1];
            p.x = f32_to_bf16(f0.x) | (f32_to_bf16(f0.y) << 16);
            p.y = f32_to_bf16(f0.z) | (f32_to_bf16(f0.w) << 16);
            p.z = f32_to_bf16(f1.x) | (f32_to_bf16(f1.y) << 16);
            p.w = f32_to_bf16(f1.z) | (f32_to_bf16(f1.w) << 16);
        }
        unsigned byte = (unsigned)(row * 256 + cc * 16);
        byte ^= (unsigned)((row & 7) << 4);
        *(uint4*)(ldsA + byte) = p;
    }
    __syncthreads();

    #pragma unroll
    for (int pass = 0; pass < 2; ++pass) {
        const bf16x8* Wf = pass ? Wf1 : Wf0;
        const float* bias = pass ? b1 : b0;
        uint2* Y = pass ? Rp : Sp;

        f32x4 acc[4][4];
        #pragma unroll
        for (int n = 0; n < 4; ++n) {
            float bv = bias[wc * 64 + n * 16 + l15];
            #pragma unroll
            for (int m = 0; m < 4; ++m) {
                acc[m][n][0] = bv; acc[m][n][1] = bv;
                acc[m][n][2] = bv; acc[m][n][3] = bv;
            }
        }
        #pragma unroll
        for (int ks = 0; ks < 4; ++ks) {
            const int kb = ks * 64 + lgp * 16;
            bf16x8 af[4], bfr[4];
            #pragma unroll
            for (int m = 0; m < 4; ++m) {
                int row = wr * 64 + m * 16 + l15;
                unsigned byte = ((unsigned)(row * 256 + kb)) ^ ((row & 7) << 4);
                af[m] = *(const bf16x8*)(ldsA + byte);
            }
            #pragma unroll
            for (int n = 0; n < 4; ++n)
                bfr[n] = Wf[((wc * 4 + n) * 4 + ks) * 64 + lane];
            #pragma unroll
            for (int m = 0; m < 4; ++m)
                #pragma unroll
                for (int n = 0; n < 4; ++n)
                    acc[m][n] = __builtin_amdgcn_mfma_f32_16x16x32_bf16(
                        af[m], bfr[n], acc[m][n], 0, 0, 0);
        }
        // store: this thread's cols are heads wc*2 + {0,1}, col-class l15
        #pragma unroll
        for (int m = 0; m < 4; ++m)
            #pragma unroll
            for (int j = 0; j < 4; ++j) {
                int row = wr * 64 + m * 16 + lgp * 4 + j;
                size_t e = rowbase + row;
                if (e >= (size_t)M) continue;
                uint2 pk;
                pk.x = f32_to_bf16(acc[m][0][j]) | (f32_to_bf16(acc[m][1][j]) << 16);
                pk.y = f32_to_bf16(acc[m][2][j]) | (f32_to_bf16(acc[m][3][j]) << 16);
                Y[e * 32 + l15 * 2 + wc] = pk;   // uints k = l15*4 + wc*2 + {0,1}
            }
    }
}

// ---------- edge GEMM: BM=64, minimal tail, 8 blocks/CU ----------
// 4 waves/block, wave w owns rows w*16..w*16+15 across all 128 cols.
// EA row layout (bf16): uint k = l15*4 + h holds cols (32h+l15, 32h+16+l15).
__global__ __launch_bounds__(256, 8) void edge_gemm(
    const float* __restrict__ X, const bf16x8* __restrict__ Wf,
    const float* __restrict__ bias,
    const int* __restrict__ senders, const unsigned* __restrict__ jof,
    const uint4* __restrict__ Sp4, uint4* __restrict__ EAp)
{
    __shared__ __align__(16) char ldsA[16384];
    const int t = threadIdx.x;
    const int lane = t & 63;
    const int wid = t >> 6;
    const int l15 = lane & 15, lgp = lane >> 4;
    const size_t rowbase = (size_t)blockIdx.x * 64;

    // ---- stage A: 64 edge rows -> bf16, XOR-swizzled (16 KB) ----
    #pragma unroll
    for (int i = 0; i < 4; ++i) {
        int c = i * 256 + t;
        int row = c >> 4, cc = c & 15;
        const float4* src = (const float4*)(X + (rowbase + row) * F + cc * 8);
        float4 f0 = src[0], f1 = src[1];
        uint4 p;
        p.x = f32_to_bf16(f0.x) | (f32_to_bf16(f0.y) << 16);
        p.y = f32_to_bf16(f0.z) | (f32_to_bf16(f0.w) << 16);
        p.z = f32_to_bf16(f1.x) | (f32_to_bf16(f1.y) << 16);
        p.w = f32_to_bf16(f1.z) | (f32_to_bf16(f1.w) << 16);
        unsigned byte = (unsigned)(row * 256 + cc * 16);
        byte ^= (unsigned)((row & 7) << 4);
        *(uint4*)(ldsA + byte) = p;
    }

    f32x4 acc[8];
    #pragma unroll
    for (int n = 0; n < 8; ++n) {
        float bv = bias[n * 16 + l15];
        acc[n][0] = bv; acc[n][1] = bv; acc[n][2] = bv; acc[n][3] = bv;
    }
    __syncthreads();

    // ---- MFMA: A from LDS, B straight from L2-resident fragment buffer ----
    #pragma unroll
    for (int ks = 0; ks < 4; ++ks) {
        int arow = wid * 16 + l15;
        unsigned abyte = ((unsigned)(arow * 256 + ks * 64 + lgp * 16))
                         ^ ((arow & 7) << 4);
        bf16x8 af = *(const bf16x8*)(ldsA + abyte);
        #pragma unroll
        for (int n = 0; n < 8; ++n) {
            bf16x8 bfr = Wf[(n * 4 + ks) * 64 + lane];
            acc[n] = __builtin_amdgcn_mfma_f32_16x16x32_bf16(af, bfr, acc[n], 0, 0, 0);
        }
    }

    // ---- tail: 4 rows per thread (row = wid*16 + lgp*4 + j) ----
    #pragma unroll
    for (int j = 0; j < 4; ++j) {
        int row = wid * 16 + lgp * 4 + j;
        size_t e = rowbase + row;
        int snd = senders[e];          // 16-lane broadcast loads
        unsigned jj = jof[e];
        uint4 sv = Sp4[(size_t)snd * 16 + l15];
        unsigned uo[4];
        #pragma unroll
        for (int h = 0; h < 4; ++h) {
            unsigned sp = (h == 0) ? sv.x : (h == 1) ? sv.y : (h == 2) ? sv.z : sv.w;
            float elo = acc[2 * h][j]     + bf16lo_to_f32(sp);
            float ehi = acc[2 * h + 1][j] + bf16hi_to_f32(sp);
            uo[h] = f32_to_bf16(elo) | (f32_to_bf16(ehi) << 16);
        }
        EAp[(size_t)jj * 16 + l15] = make_uint4(uo[0], uo[1], uo[2], uo[3]);
    }
}

// ---------- fused logit + single-pass softmax + aggregate ----------
// One wave per receiver; unrolled x2 (two independent latency chains).
__global__ __launch_bounds__(256) void agg_kernel(
    const unsigned* __restrict__ rowptr,
    const uint4* __restrict__ Rp4,
    const float* __restrict__ attw, const float* __restrict__ attb,
    const unsigned* __restrict__ EA, float* __restrict__ out)
{
    const int lane = threadIdx.x & 63;
    const int r = blockIdx.x * 4 + (threadIdx.x >> 6);
    if (r >= NN) return;
    const unsigned start = rowptr[r], end = rowptr[r + 1];

    // EA uint k = lane: l15c = lane>>2, h = lane&3, cols (32h+l15c, +16)
    const int h    = lane & 3;
    const int l15c = lane >> 2;
    const int c0   = 32 * h + l15c;

    if (start == end) {
        out[(size_t)r * HD + c0]      = 0.f;
        out[(size_t)r * HD + c0 + 16] = 0.f;
        return;
    }

    uint4 rv4 = Rp4[(size_t)r * 16 + l15c];
    unsigned rp = (h == 0) ? rv4.x : (h == 1) ? rv4.y : (h == 2) ? rv4.z : rv4.w;
    const float rlo = bf16lo_to_f32(rp), rhi = bf16hi_to_f32(rp);
    const float aw0 = attw[l15c];
    const float aw1 = attw[l15c + 16];
    const float ab0 = attb[0];
    const unsigned* ea = EA + lane;

    float ax0 = 0.f, ay0 = 0.f, dn0 = 0.f;
    float ax1 = 0.f, ay1 = 0.f, dn1 = 0.f;
    unsigned j = start;
    for (; j + 2 <= end; j += 2) {
        unsigned p0 = ea[(size_t)j * 64];
        unsigned p1 = ea[(size_t)(j + 1) * 64];
        float e0l = bf16lo_to_f32(p0), e0h = bf16hi_to_f32(p0);
        float e1l = bf16lo_to_f32(p1), e1h = bf16hi_to_f32(p1);
        float t0 = mish_f(e0l + rlo) * aw0 + mish_f(e0h + rhi) * aw1;
        float t1 = mish_f(e1l + rlo) * aw0 + mish_f(e1h + rhi) * aw1;
        t0 += __shfl_xor(t0, 4);   t1 += __shfl_xor(t1, 4);
        t0 += __shfl_xor(t0, 8);   t1 += __shfl_xor(t1, 8);
        t0 += __shfl_xor(t0, 16);  t1 += __shfl_xor(t1, 16);
        t0 += __shfl_xor(t0, 32);  t1 += __shfl_xor(t1, 32);
        float w0 = __expf(t0 + ab0);
        float w1 = __expf(t1 + ab0);
        dn0 += w0;  ax0 += w0 * e0l;  ay0 += w0 * e0h;
        dn1 += w1;  ax1 += w1 * e1l;  ay1 += w1 * e1h;
    }
    if (j < end) {
        unsigned p0 = ea[(size_t)j * 64];
        float e0l = bf16lo_to_f32(p0), e0h = bf16hi_to_f32(p0);
        float t0 = mish_f(e0l + rlo) * aw0 + mish_f(e0h + rhi) * aw1;
        t0 += __shfl_xor(t0, 4);
        t0 += __shfl_xor(t0, 8);
        t0 += __shfl_xor(t0, 16);
        t0 += __shfl_xor(t0, 32);
        float w0 = __expf(t0 + ab0);
        dn0 += w0;  ax0 += w0 * e0l;  ay0 += w0 * e0h;
    }
    float rd = 1.f / (dn0 + dn1);
    out[(size_t)r * HD + c0]      = (ax0 + ax1) * rd;
    out[(size_t)r * HD + c0 + 16] = (ay0 + ay1) * rd;
}

// ---------- host ----------
extern "C" void kernel_launch(void* const* d_in, const int* in_sizes, int n_in,
                              void* d_out, int out_size, void* d_ws, size_t ws_size,
                              hipStream_t stream) {
    const float* nodes = (const float*)d_in[0];
    const float* edges = (const float*)d_in[1];
    const float* Ws_k  = (const float*)d_in[2];
    const float* Ws_b  = (const float*)d_in[3];
    const float* Wr_k  = (const float*)d_in[4];
    const float* Wr_b  = (const float*)d_in[5];
    const float* We_k  = (const float*)d_in[6];
    const float* We_b  = (const float*)d_in[7];
    const float* attw  = (const float*)d_in[8];
    const float* attb  = (const float*)d_in[9];
    const int* senders   = (const int*)d_in[10];
    const int* receivers = (const int*)d_in[11];
    float* out = (float*)d_out;

    char* ws = (char*)d_ws;
    const size_t CNT_OFF  = 0;            // 200,000
    const size_t CNT2_OFF = 200000;       // 200,000
    const size_t RP_OFF   = 400000;       // 200,004
    const size_t BS_OFF   = 600004;       // 784 (bsum) + 784 (boff) -> pad
    const size_t JOF_OFF  = 700000;       // 3,200,000 -> ends 3,900,000
    const size_t WF_OFF   = 3900000;      // 98,304    -> ends 3,998,304
    const size_t SP_OFF   = 4000000;      // 12,800,000 (bf16) -> 16.8e6
    const size_t RPP_OFF  = 16800000;     // 12,800,000 -> 29.6e6
    const size_t EA_OFF   = 29600000;     // 204,800,000 -> 234.4e6

    unsigned* cnt    = (unsigned*)(ws + CNT_OFF);
    unsigned* cnt2   = (unsigned*)(ws + CNT2_OFF);
    unsigned* rowptr = (unsigned*)(ws + RP_OFF);
    unsigned* bsum   = (unsigned*)(ws + BS_OFF);
    unsigned* boff   = bsum + 256;
    unsigned* jof    = (unsigned*)(ws + JOF_OFF);
    uint4*    Wf     = (uint4*)(ws + WF_OFF);
    uint2*    Sp     = (uint2*)(ws + SP_OFF);
    uint2*    Rp     = (uint2*)(ws + RPP_OFF);
    unsigned* EA     = (unsigned*)(ws + EA_OFF);
    (void)ws_size;

    const int NB = (NN + 255) / 256;   // 196 scan blocks

    // weights -> bf16 fragment order (Ws, Wr, We)
    prep_w<<<3, 256, 0, stream>>>(Ws_k, Wr_k, We_k, Wf);

    // CSR build (rowptr + inverse perm map jof), multi-block scan
    hipMemsetAsync(ws + CNT_OFF, 0, 400000, stream);   // cnt + cnt2
    hist_kernel<<<(NE + 255) / 256, 256, 0, stream>>>(receivers, cnt);
    scan1_kernel<<<NB, 256, 0, stream>>>(cnt, rowptr, bsum);
    scan2_kernel<<<1, 256, 0, stream>>>(bsum, boff, NB, rowptr);
    scan3_kernel<<<NB, 256, 0, stream>>>(rowptr, boff);
    scatter_kernel<<<(NE + 255) / 256, 256, 0, stream>>>(receivers, rowptr, cnt2, jof);

    // both node projections (bf16 head-interleaved packed output)
    proj_both<<<(NN + 127) / 128, 256, 0, stream>>>(
        nodes, (const bf16x8*)Wf, (const bf16x8*)(Wf + 2048),
        Ws_b, Wr_b, NN, Sp, Rp);

    // edge GEMM: EA written at perm positions (no logits, no R gather)
    edge_gemm<<<NE / 64, 256, 0, stream>>>(
        edges, (const bf16x8*)(Wf + 4096), We_b,
        senders, jof, (const uint4*)Sp, (uint4*)EA);

    // fused logit + single-pass softmax + aggregation
    agg_kernel<<<(NN + 3) / 4, 256, 0, stream>>>(
        rowptr, (const uint4*)Rp, attw, attb, EA, out);
}